// Round 8
// baseline (96.930 us; speedup 1.0000x reference)
//
#include <hip/hip_runtime.h>
#include <stdint.h>

#define LSEQ 1024
#define EDIM 32
#define NDIM 64

typedef __attribute__((ext_vector_type(8))) short short8;
typedef __attribute__((ext_vector_type(4))) float f32x4;

static __device__ __forceinline__ unsigned short f2bf(float f) {
    unsigned int u = __float_as_uint(f);
    u += 0x7FFFu + ((u >> 16) & 1u);
    return (unsigned short)(u >> 16);
}

// Kernel A: niB = node@Wi + b_pair, njB = node@Wj (f32); wpT = (Wp + I)^T in bf16
__global__ __launch_bounds__(256) void evo_pre(
    const float* __restrict__ node,   // [1024][64]
    const float* __restrict__ Wpair,  // [160][32]
    const float* __restrict__ bpair,  // [32]
    float* __restrict__ niB,          // [1024][32]
    float* __restrict__ njB,          // [1024][32]
    unsigned short* __restrict__ wpT) // [32][32] bf16, row f, col e
{
    int g = blockIdx.x * 256 + threadIdx.x;
    if (g < LSEQ * EDIM) {
        int i = g >> 5, f = g & 31;
        float acci = bpair[f];
        float accj = 0.0f;
        const float* nrow = node + i * NDIM;
        #pragma unroll
        for (int k = 0; k < NDIM; ++k) {
            float nv = nrow[k];
            acci += nv * Wpair[k * 32 + f];
            accj += nv * Wpair[(64 + k) * 32 + f];
        }
        niB[g] = acci;
        njB[g] = accj;
    } else {
        int idx = g - LSEQ * EDIM;
        if (idx < EDIM * EDIM) {
            int f = idx >> 5, e = idx & 31;
            float v = Wpair[(128 + e) * 32 + f];
            if (e == f) v += 1.0f;  // fold the +pair residual into the matmul
            wpT[f * 32 + e] = f2bf(v);
        }
    }
}

// Kernel B: 2048 blocks = 2 per row i; each block (4 waves) owns a 512-j span,
// each wave a 128-j span. D[f][j] = (Wp+I)^T @ pair_row^T via MFMA + niB[i] +
// njB[j]; regular stores; per-block j-sum partial -> ws (no atomics).
__global__ __launch_bounds__(256, 8) void evo_main(
    const float* __restrict__ pair,   // [1024][1024][32]
    const float* __restrict__ niB,    // [1024][32]
    const float* __restrict__ njB,    // [1024][32]
    const unsigned short* __restrict__ wpT,  // [32][32] bf16
    float* __restrict__ partial,      // [2048][32]
    float* __restrict__ out_pair)     // [1024][1024][32]
{
    __shared__ float red[4][32];

    const int blk  = blockIdx.x;
    const int i    = blk >> 1;
    const int h    = blk & 1;     // which 512-j half of the row
    const int tid  = threadIdx.x;
    const int wave = tid >> 6;
    const int lane = tid & 63;
    const int c    = lane & 15;   // MFMA col select (j-local) / A row select
    const int a    = lane >> 4;   // contiguous 8-wide K-chunk select / D row group

    // A fragments: wpT rows f = c and c+16, K-chunk a*8..a*8+7 (held all kernel)
    const short8 af0 = *(const short8*)(wpT + c * 32 + a * 8);
    const short8 af1 = *(const short8*)(wpT + (c + 16) * 32 + a * 8);
    // niB[i][f] for f = 4a+r and 16+4a+r: constant per lane
    const f32x4 ni0 = *(const f32x4*)(niB + i * 32 + 4 * a);
    const f32x4 ni1 = *(const f32x4*)(niB + i * 32 + 4 * a + 16);

    f32x4 sum0 = {0.f, 0.f, 0.f, 0.f};
    f32x4 sum1 = {0.f, 0.f, 0.f, 0.f};

    const int jw = (h << 9) + (wave << 7);  // this wave's 128-j span start
    // per-lane element offset for iteration t: pair row jw + t*16 + c
    const size_t base = ((((size_t)i) << 10) + (size_t)(jw + c)) << 5;
    const float* pin  = pair + base + a * 8;      // two f32x4 at +0 and +4
    const float* njp  = njB + (size_t)(jw + c) * 32 + 4 * a;
    float*       pout = out_pair + base + 4 * a;  // f32x4 at +0 and +16

    // 1-deep software prefetch: keep next tile's loads in flight during MFMA
    f32x4 pa = *(const f32x4*)(pin);
    f32x4 pb = *(const f32x4*)(pin + 4);

    #pragma unroll
    for (int t = 0; t < 8; ++t) {
        const int tn = (t < 7) ? (t + 1) : 7;     // 16 rows * 32 el = 512 per t
        const f32x4 na = *(const f32x4*)(pin + tn * 512);
        const f32x4 nb = *(const f32x4*)(pin + tn * 512 + 4);

        short8 bfrag;
        bfrag[0] = (short)f2bf(pa.x); bfrag[1] = (short)f2bf(pa.y);
        bfrag[2] = (short)f2bf(pa.z); bfrag[3] = (short)f2bf(pa.w);
        bfrag[4] = (short)f2bf(pb.x); bfrag[5] = (short)f2bf(pb.y);
        bfrag[6] = (short)f2bf(pb.z); bfrag[7] = (short)f2bf(pb.w);
        const f32x4 z = {0.f, 0.f, 0.f, 0.f};
        f32x4 acc0 = __builtin_amdgcn_mfma_f32_16x16x32_bf16(af0, bfrag, z, 0, 0, 0);
        f32x4 acc1 = __builtin_amdgcn_mfma_f32_16x16x32_bf16(af1, bfrag, z, 0, 0, 0);
        const f32x4 nj0 = *(const f32x4*)(njp + t * 512);
        const f32x4 nj1 = *(const f32x4*)(njp + t * 512 + 16);
        const f32x4 o0 = acc0 + ni0 + nj0;
        const f32x4 o1 = acc1 + ni1 + nj1;
        sum0 += o0;
        sum1 += o1;
        *(f32x4*)(pout + t * 512)      = o0;
        *(f32x4*)(pout + t * 512 + 16) = o1;
        pa = na;
        pb = nb;
    }

    // reduce j-sums over the 16 c-lanes (low 4 lane bits)
    for (int m = 1; m < 16; m <<= 1) {
        sum0.x += __shfl_xor(sum0.x, m); sum0.y += __shfl_xor(sum0.y, m);
        sum0.z += __shfl_xor(sum0.z, m); sum0.w += __shfl_xor(sum0.w, m);
        sum1.x += __shfl_xor(sum1.x, m); sum1.y += __shfl_xor(sum1.y, m);
        sum1.z += __shfl_xor(sum1.z, m); sum1.w += __shfl_xor(sum1.w, m);
    }
    if (c == 0) {
        red[wave][4 * a + 0]      = sum0.x;
        red[wave][4 * a + 1]      = sum0.y;
        red[wave][4 * a + 2]      = sum0.z;
        red[wave][4 * a + 3]      = sum0.w;
        red[wave][16 + 4 * a + 0] = sum1.x;
        red[wave][16 + 4 * a + 1] = sum1.y;
        red[wave][16 + 4 * a + 2] = sum1.z;
        red[wave][16 + 4 * a + 3] = sum1.w;
    }
    __syncthreads();
    if (tid < 32) {
        partial[blk * 32 + tid] = red[0][tid] + red[1][tid] + red[2][tid] + red[3][tid];
    }
}

// Kernel C: node update + LayerNorm. One block (1 wave) per row i.
__global__ __launch_bounds__(64) void evo_finish(
    const float* __restrict__ node,     // [1024][64]
    const float* __restrict__ partial,  // [2048][32]
    const float* __restrict__ Wnode,    // [96][64]
    const float* __restrict__ bnode,    // [64]
    const float* __restrict__ lnsc,     // [64]
    const float* __restrict__ lnof,     // [64]
    float* __restrict__ out_node)       // [1024][64]
{
    __shared__ float node_f[64];
    __shared__ float p2n[32];
    const int i   = blockIdx.x;
    const int tid = threadIdx.x;

    node_f[tid] = node[i * 64 + tid];
    if (tid < 32) {
        p2n[tid] = (partial[(2 * i) * 32 + tid] + partial[(2 * i + 1) * 32 + tid])
                   * (1.0f / 1024.0f);
    }
    __syncthreads();

    float acc = node_f[tid] + bnode[tid];
    #pragma unroll 8
    for (int k = 0; k < 64; ++k)
        acc += node_f[k] * Wnode[k * 64 + tid];
    #pragma unroll 8
    for (int k = 0; k < 32; ++k)
        acc += p2n[k] * Wnode[(64 + k) * 64 + tid];

    float s = acc, s2 = acc * acc;
    for (int m = 1; m < 64; m <<= 1) {
        s  += __shfl_xor(s, m);
        s2 += __shfl_xor(s2, m);
    }
    const float mean = s * (1.0f / 64.0f);
    const float var  = s2 * (1.0f / 64.0f) - mean * mean;
    const float y = (acc - mean) * rsqrtf(var + 1e-5f) * lnsc[tid] + lnof[tid];
    out_node[i * 64 + tid] = y;
}

extern "C" void kernel_launch(void* const* d_in, const int* in_sizes, int n_in,
                              void* d_out, int out_size, void* d_ws, size_t ws_size,
                              hipStream_t stream) {
    const float* node  = (const float*)d_in[0];
    const float* pair  = (const float*)d_in[1];
    const float* Wpair = (const float*)d_in[2];
    const float* bpair = (const float*)d_in[3];
    const float* Wnode = (const float*)d_in[4];
    const float* bnode = (const float*)d_in[5];
    const float* lnsc  = (const float*)d_in[6];
    const float* lnof  = (const float*)d_in[7];

    float* niB = (float*)d_ws;                        // [1024][32] f32
    float* njB = niB + LSEQ * EDIM;                   // [1024][32] f32
    unsigned short* wpT = (unsigned short*)(njB + LSEQ * EDIM);  // [32][32] bf16 (2 KB)
    float* partial = (float*)(wpT + EDIM * EDIM);     // [2048][32] f32 (256 KB)

    float* out_node = (float*)d_out;
    float* out_pair = out_node + LSEQ * NDIM;

    evo_pre<<<132, 256, 0, stream>>>(node, Wpair, bpair, niB, njB, wpT);
    evo_main<<<2 * LSEQ, 256, 0, stream>>>(pair, niB, njB, wpT, partial, out_pair);
    evo_finish<<<LSEQ, 64, 0, stream>>>(node, partial, Wnode, bnode, lnsc, lnof,
                                        out_node);
}

// Round 9
// 70.205 us; speedup vs baseline: 1.3807x; 1.3807x over previous
//
#include <hip/hip_runtime.h>
#include <stdint.h>

#define LSEQ 1024
#define EDIM 32
#define NDIM 64

typedef __attribute__((ext_vector_type(8))) short short8;
typedef __attribute__((ext_vector_type(4))) float f32x4;

static __device__ __forceinline__ unsigned short f2bf(float f) {
    unsigned int u = __float_as_uint(f);
    u += 0x7FFFu + ((u >> 16) & 1u);
    return (unsigned short)(u >> 16);
}

// Kernel A: niB = node@Wi + b_pair, njB = node@Wj (f32); wpT = (Wp + I)^T in bf16
__global__ __launch_bounds__(256) void evo_pre(
    const float* __restrict__ node,   // [1024][64]
    const float* __restrict__ Wpair,  // [160][32]
    const float* __restrict__ bpair,  // [32]
    float* __restrict__ niB,          // [1024][32]
    float* __restrict__ njB,          // [1024][32]
    unsigned short* __restrict__ wpT) // [32][32] bf16, row f, col e
{
    int g = blockIdx.x * 256 + threadIdx.x;
    if (g < LSEQ * EDIM) {
        int i = g >> 5, f = g & 31;
        float acci = bpair[f];
        float accj = 0.0f;
        const float* nrow = node + i * NDIM;
        #pragma unroll
        for (int k = 0; k < NDIM; ++k) {
            float nv = nrow[k];
            acci += nv * Wpair[k * 32 + f];
            accj += nv * Wpair[(64 + k) * 32 + f];
        }
        niB[g] = acci;
        njB[g] = accj;
    } else {
        int idx = g - LSEQ * EDIM;
        if (idx < EDIM * EDIM) {
            int f = idx >> 5, e = idx & 31;
            float v = Wpair[(128 + e) * 32 + f];
            if (e == f) v += 1.0f;  // fold the +pair residual into the matmul
            wpT[f * 32 + e] = f2bf(v);
        }
    }
}

// Kernel B: 2048 blocks = 2 per row i; block (4 waves) owns 512 j's, wave owns 128.
// MFMA epilogue values are staged through a per-wave LDS buffer (XOR-swizzled),
// then stored linearly so every 128-B output line is written by ONE instruction.
__global__ __launch_bounds__(256, 4) void evo_main(
    const float* __restrict__ pair,   // [1024][1024][32]
    const float* __restrict__ niB,    // [1024][32]
    const float* __restrict__ njB,    // [1024][32]
    const unsigned short* __restrict__ wpT,  // [32][32] bf16
    float* __restrict__ partial,      // [2048][32]
    float* __restrict__ out_pair)     // [1024][1024][32]
{
    __shared__ float stage[4][512];   // per-wave 2-KB staging tile
    __shared__ float red[4][32];

    const int blk  = blockIdx.x;
    const int i    = blk >> 1;
    const int h    = blk & 1;     // which 512-j half of the row
    const int tid  = threadIdx.x;
    const int wave = tid >> 6;
    const int lane = tid & 63;
    const int c    = lane & 15;   // MFMA col select (j-local) / A row select
    const int a    = lane >> 4;   // contiguous 8-wide K-chunk select / D row group

    // A fragments: wpT rows f = c and c+16, K-chunk a*8..a*8+7 (held all kernel)
    const short8 af0 = *(const short8*)(wpT + c * 32 + a * 8);
    const short8 af1 = *(const short8*)(wpT + (c + 16) * 32 + a * 8);
    // niB[i][f] for f = 4a+r and 16+4a+r: constant per lane
    const f32x4 ni0 = *(const f32x4*)(niB + i * 32 + 4 * a);
    const f32x4 ni1 = *(const f32x4*)(niB + i * 32 + 4 * a + 16);

    f32x4 sum0 = {0.f, 0.f, 0.f, 0.f};
    f32x4 sum1 = {0.f, 0.f, 0.f, 0.f};

    const int jw = (h << 9) + (wave << 7);  // this wave's 128-j span start
    const size_t base = ((((size_t)i) << 10) + (size_t)(jw + c)) << 5;
    const float* pin = pair + base + a * 8;          // two f32x4 at +0 and +4
    const float* njp = njB + (size_t)(jw + c) * 32 + 4 * a;

    // LDS staging addresses. Logical: row c gets floats [4a,4a+4) (o0) and
    // [16+4a,+4) (o1). Slot XOR-swizzled by row to spread banks.
    const int key = (c & 7) << 2;
    float* wr0 = &stage[wave][c * 32 + ((4 * a) ^ key)];
    float* wr1 = &stage[wave][c * 32 + ((16 + 4 * a) ^ key)];
    // Linear read-back: chunk0 = floats [lane*4, +4) (rows 0-7),
    // chunk1 = floats [256 + lane*4, +4) (rows 8-15); same XOR per row.
    const int r0 = lane >> 3, oR = (lane & 7) * 4, keyR = (r0 & 7) << 2;
    const float* rd0 = &stage[wave][r0 * 32 + (oR ^ keyR)];
    const float* rd1 = &stage[wave][(r0 + 8) * 32 + (oR ^ keyR)];
    // Wave's contiguous 2-KB output region for iteration t (float offset):
    float* preg = out_pair + ((((size_t)i) << 10) + (size_t)jw) * 32 + lane * 4;

    // 1-deep software prefetch
    f32x4 pa = *(const f32x4*)(pin);
    f32x4 pb = *(const f32x4*)(pin + 4);

    #pragma unroll
    for (int t = 0; t < 8; ++t) {
        const int tn = (t < 7) ? (t + 1) : 7;     // 16 rows * 32 el = 512 per t
        const f32x4 na = *(const f32x4*)(pin + tn * 512);
        const f32x4 nb = *(const f32x4*)(pin + tn * 512 + 4);

        short8 bfrag;
        bfrag[0] = (short)f2bf(pa.x); bfrag[1] = (short)f2bf(pa.y);
        bfrag[2] = (short)f2bf(pa.z); bfrag[3] = (short)f2bf(pa.w);
        bfrag[4] = (short)f2bf(pb.x); bfrag[5] = (short)f2bf(pb.y);
        bfrag[6] = (short)f2bf(pb.z); bfrag[7] = (short)f2bf(pb.w);
        const f32x4 z = {0.f, 0.f, 0.f, 0.f};
        f32x4 acc0 = __builtin_amdgcn_mfma_f32_16x16x32_bf16(af0, bfrag, z, 0, 0, 0);
        f32x4 acc1 = __builtin_amdgcn_mfma_f32_16x16x32_bf16(af1, bfrag, z, 0, 0, 0);
        const f32x4 nj0 = *(const f32x4*)(njp + t * 512);
        const f32x4 nj1 = *(const f32x4*)(njp + t * 512 + 16);
        const f32x4 o0 = acc0 + ni0 + nj0;
        const f32x4 o1 = acc1 + ni1 + nj1;
        sum0 += o0;
        sum1 += o1;

        // stage 2-KB tile in LDS, then store it linearly (full 128-B lines)
        *(f32x4*)wr0 = o0;
        *(f32x4*)wr1 = o1;
        *(f32x4*)(preg + t * 512)       = *(const f32x4*)rd0;
        *(f32x4*)(preg + t * 512 + 256) = *(const f32x4*)rd1;

        pa = na;
        pb = nb;
    }

    // reduce j-sums over the 16 c-lanes (low 4 lane bits)
    for (int m = 1; m < 16; m <<= 1) {
        sum0.x += __shfl_xor(sum0.x, m); sum0.y += __shfl_xor(sum0.y, m);
        sum0.z += __shfl_xor(sum0.z, m); sum0.w += __shfl_xor(sum0.w, m);
        sum1.x += __shfl_xor(sum1.x, m); sum1.y += __shfl_xor(sum1.y, m);
        sum1.z += __shfl_xor(sum1.z, m); sum1.w += __shfl_xor(sum1.w, m);
    }
    if (c == 0) {
        red[wave][4 * a + 0]      = sum0.x;
        red[wave][4 * a + 1]      = sum0.y;
        red[wave][4 * a + 2]      = sum0.z;
        red[wave][4 * a + 3]      = sum0.w;
        red[wave][16 + 4 * a + 0] = sum1.x;
        red[wave][16 + 4 * a + 1] = sum1.y;
        red[wave][16 + 4 * a + 2] = sum1.z;
        red[wave][16 + 4 * a + 3] = sum1.w;
    }
    __syncthreads();
    if (tid < 32) {
        partial[blk * 32 + tid] = red[0][tid] + red[1][tid] + red[2][tid] + red[3][tid];
    }
}

// Kernel C: node update + LayerNorm. One block (1 wave) per row i.
__global__ __launch_bounds__(64) void evo_finish(
    const float* __restrict__ node,     // [1024][64]
    const float* __restrict__ partial,  // [2048][32]
    const float* __restrict__ Wnode,    // [96][64]
    const float* __restrict__ bnode,    // [64]
    const float* __restrict__ lnsc,     // [64]
    const float* __restrict__ lnof,     // [64]
    float* __restrict__ out_node)       // [1024][64]
{
    __shared__ float node_f[64];
    __shared__ float p2n[32];
    const int i   = blockIdx.x;
    const int tid = threadIdx.x;

    node_f[tid] = node[i * 64 + tid];
    if (tid < 32) {
        p2n[tid] = (partial[(2 * i) * 32 + tid] + partial[(2 * i + 1) * 32 + tid])
                   * (1.0f / 1024.0f);
    }
    __syncthreads();

    float acc = node_f[tid] + bnode[tid];
    #pragma unroll 8
    for (int k = 0; k < 64; ++k)
        acc += node_f[k] * Wnode[k * 64 + tid];
    #pragma unroll 8
    for (int k = 0; k < 32; ++k)
        acc += p2n[k] * Wnode[(64 + k) * 64 + tid];

    float s = acc, s2 = acc * acc;
    for (int m = 1; m < 64; m <<= 1) {
        s  += __shfl_xor(s, m);
        s2 += __shfl_xor(s2, m);
    }
    const float mean = s * (1.0f / 64.0f);
    const float var  = s2 * (1.0f / 64.0f) - mean * mean;
    const float y = (acc - mean) * rsqrtf(var + 1e-5f) * lnsc[tid] + lnof[tid];
    out_node[i * 64 + tid] = y;
}

extern "C" void kernel_launch(void* const* d_in, const int* in_sizes, int n_in,
                              void* d_out, int out_size, void* d_ws, size_t ws_size,
                              hipStream_t stream) {
    const float* node  = (const float*)d_in[0];
    const float* pair  = (const float*)d_in[1];
    const float* Wpair = (const float*)d_in[2];
    const float* bpair = (const float*)d_in[3];
    const float* Wnode = (const float*)d_in[4];
    const float* bnode = (const float*)d_in[5];
    const float* lnsc  = (const float*)d_in[6];
    const float* lnof  = (const float*)d_in[7];

    float* niB = (float*)d_ws;                        // [1024][32] f32
    float* njB = niB + LSEQ * EDIM;                   // [1024][32] f32
    unsigned short* wpT = (unsigned short*)(njB + LSEQ * EDIM);  // [32][32] bf16 (2 KB)
    float* partial = (float*)(wpT + EDIM * EDIM);     // [2048][32] f32 (256 KB)

    float* out_node = (float*)d_out;
    float* out_pair = out_node + LSEQ * NDIM;

    evo_pre<<<132, 256, 0, stream>>>(node, Wpair, bpair, niB, njB, wpT);
    evo_main<<<2 * LSEQ, 256, 0, stream>>>(pair, niB, njB, wpT, partial, out_pair);
    evo_finish<<<LSEQ, 64, 0, stream>>>(node, partial, Wnode, bnode, lnsc, lnof,
                                        out_node);
}

// Round 10
// 66.400 us; speedup vs baseline: 1.4598x; 1.0573x over previous
//
#include <hip/hip_runtime.h>
#include <stdint.h>

#define LSEQ 1024
#define EDIM 32
#define NDIM 64

typedef __attribute__((ext_vector_type(8))) short short8;
typedef __attribute__((ext_vector_type(4))) float f32x4;

static __device__ __forceinline__ unsigned short f2bf(float f) {
    unsigned int u = __float_as_uint(f);
    u += 0x7FFFu + ((u >> 16) & 1u);
    return (unsigned short)(u >> 16);
}

// Kernel A: niB = node@Wi + b_pair, njB = node@Wj (f32); wpT = (Wp + I)^T in bf16
__global__ __launch_bounds__(256) void evo_pre(
    const float* __restrict__ node,   // [1024][64]
    const float* __restrict__ Wpair,  // [160][32]
    const float* __restrict__ bpair,  // [32]
    float* __restrict__ niB,          // [1024][32]
    float* __restrict__ njB,          // [1024][32]
    unsigned short* __restrict__ wpT) // [32][32] bf16, row f, col e
{
    int g = blockIdx.x * 256 + threadIdx.x;
    if (g < LSEQ * EDIM) {
        int i = g >> 5, f = g & 31;
        float acci = bpair[f];
        float accj = 0.0f;
        const float* nrow = node + i * NDIM;
        #pragma unroll
        for (int k = 0; k < NDIM; ++k) {
            float nv = nrow[k];
            acci += nv * Wpair[k * 32 + f];
            accj += nv * Wpair[(64 + k) * 32 + f];
        }
        niB[g] = acci;
        njB[g] = accj;
    } else {
        int idx = g - LSEQ * EDIM;
        if (idx < EDIM * EDIM) {
            int f = idx >> 5, e = idx & 31;
            float v = Wpair[(128 + e) * 32 + f];
            if (e == f) v += 1.0f;  // fold the +pair residual into the matmul
            wpT[f * 32 + e] = f2bf(v);
        }
    }
}

// Kernel B: 2048 blocks = 2 per row i; block (4 waves) owns 512 j's, wave owns 128.
// Pair prefetched 2-deep, nj 1-deep: steady-state waitcnt never drains the
// in-flight HBM loads. Epilogue staged via per-wave XOR-swizzled LDS tile,
// stored linearly (every 128-B line written by one instruction).
__global__ __launch_bounds__(256, 4) void evo_main(
    const float* __restrict__ pair,   // [1024][1024][32]
    const float* __restrict__ niB,    // [1024][32]
    const float* __restrict__ njB,    // [1024][32]
    const unsigned short* __restrict__ wpT,  // [32][32] bf16
    float* __restrict__ partial,      // [2048][32]
    float* __restrict__ out_pair)     // [1024][1024][32]
{
    __shared__ float stage[4][512];   // per-wave 2-KB staging tile
    __shared__ float red[4][32];

    const int blk  = blockIdx.x;
    const int i    = blk >> 1;
    const int h    = blk & 1;     // which 512-j half of the row
    const int tid  = threadIdx.x;
    const int wave = tid >> 6;
    const int lane = tid & 63;
    const int c    = lane & 15;   // MFMA col select (j-local) / A row select
    const int a    = lane >> 4;   // contiguous 8-wide K-chunk select / D row group

    // A fragments: wpT rows f = c and c+16, K-chunk a*8..a*8+7 (held all kernel)
    const short8 af0 = *(const short8*)(wpT + c * 32 + a * 8);
    const short8 af1 = *(const short8*)(wpT + (c + 16) * 32 + a * 8);
    // niB[i][f] for f = 4a+r and 16+4a+r: constant per lane
    const f32x4 ni0 = *(const f32x4*)(niB + i * 32 + 4 * a);
    const f32x4 ni1 = *(const f32x4*)(niB + i * 32 + 4 * a + 16);

    f32x4 sum0 = {0.f, 0.f, 0.f, 0.f};
    f32x4 sum1 = {0.f, 0.f, 0.f, 0.f};

    const int jw = (h << 9) + (wave << 7);  // this wave's 128-j span start
    const size_t base = ((((size_t)i) << 10) + (size_t)(jw + c)) << 5;
    const float* pin = pair + base + a * 8;          // two f32x4 at +0 and +4
    const float* njp = njB + (size_t)(jw + c) * 32 + 4 * a;

    // LDS staging addresses (identical to R9; 0 bank conflicts measured)
    const int key = (c & 7) << 2;
    float* wr0 = &stage[wave][c * 32 + ((4 * a) ^ key)];
    float* wr1 = &stage[wave][c * 32 + ((16 + 4 * a) ^ key)];
    const int r0 = lane >> 3, oR = (lane & 7) * 4, keyR = (r0 & 7) << 2;
    const float* rd0 = &stage[wave][r0 * 32 + (oR ^ keyR)];
    const float* rd1 = &stage[wave][(r0 + 8) * 32 + (oR ^ keyR)];
    float* preg = out_pair + ((((size_t)i) << 10) + (size_t)jw) * 32 + lane * 4;

    // 2-deep pair prefetch + 1-deep nj prefetch
    f32x4 pA[2], pB[2], jA[2], jB[2];
    pA[0] = *(const f32x4*)(pin);
    pB[0] = *(const f32x4*)(pin + 4);
    pA[1] = *(const f32x4*)(pin + 512);
    pB[1] = *(const f32x4*)(pin + 512 + 4);
    jA[0] = *(const f32x4*)(njp);
    jB[0] = *(const f32x4*)(njp + 16);

    #pragma unroll
    for (int t = 0; t < 8; ++t) {
        const int cur = t & 1;
        // issue nj(t+1) first (L2-resident, consumed next iter)
        if (t < 7) {
            jA[cur ^ 1] = *(const f32x4*)(njp + (t + 1) * 512);
            jB[cur ^ 1] = *(const f32x4*)(njp + (t + 1) * 512 + 16);
        }

        // consume pair(t) — issued 2 iterations ago
        short8 bfrag;
        bfrag[0] = (short)f2bf(pA[cur].x); bfrag[1] = (short)f2bf(pA[cur].y);
        bfrag[2] = (short)f2bf(pA[cur].z); bfrag[3] = (short)f2bf(pA[cur].w);
        bfrag[4] = (short)f2bf(pB[cur].x); bfrag[5] = (short)f2bf(pB[cur].y);
        bfrag[6] = (short)f2bf(pB[cur].z); bfrag[7] = (short)f2bf(pB[cur].w);

        // refill the just-consumed slot with pair(t+2)
        if (t < 6) {
            pA[cur] = *(const f32x4*)(pin + (t + 2) * 512);
            pB[cur] = *(const f32x4*)(pin + (t + 2) * 512 + 4);
        }

        const f32x4 z = {0.f, 0.f, 0.f, 0.f};
        f32x4 acc0 = __builtin_amdgcn_mfma_f32_16x16x32_bf16(af0, bfrag, z, 0, 0, 0);
        f32x4 acc1 = __builtin_amdgcn_mfma_f32_16x16x32_bf16(af1, bfrag, z, 0, 0, 0);
        const f32x4 o0 = acc0 + ni0 + jA[cur];
        const f32x4 o1 = acc1 + ni1 + jB[cur];
        sum0 += o0;
        sum1 += o1;

        // stage 2-KB tile in LDS, then store linearly (full 128-B lines)
        *(f32x4*)wr0 = o0;
        *(f32x4*)wr1 = o1;
        *(f32x4*)(preg + t * 512)       = *(const f32x4*)rd0;
        *(f32x4*)(preg + t * 512 + 256) = *(const f32x4*)rd1;
    }

    // reduce j-sums over the 16 c-lanes (low 4 lane bits)
    for (int m = 1; m < 16; m <<= 1) {
        sum0.x += __shfl_xor(sum0.x, m); sum0.y += __shfl_xor(sum0.y, m);
        sum0.z += __shfl_xor(sum0.z, m); sum0.w += __shfl_xor(sum0.w, m);
        sum1.x += __shfl_xor(sum1.x, m); sum1.y += __shfl_xor(sum1.y, m);
        sum1.z += __shfl_xor(sum1.z, m); sum1.w += __shfl_xor(sum1.w, m);
    }
    if (c == 0) {
        red[wave][4 * a + 0]      = sum0.x;
        red[wave][4 * a + 1]      = sum0.y;
        red[wave][4 * a + 2]      = sum0.z;
        red[wave][4 * a + 3]      = sum0.w;
        red[wave][16 + 4 * a + 0] = sum1.x;
        red[wave][16 + 4 * a + 1] = sum1.y;
        red[wave][16 + 4 * a + 2] = sum1.z;
        red[wave][16 + 4 * a + 3] = sum1.w;
    }
    __syncthreads();
    if (tid < 32) {
        partial[blk * 32 + tid] = red[0][tid] + red[1][tid] + red[2][tid] + red[3][tid];
    }
}

// Kernel C: node update + LayerNorm. One block (1 wave) per row i.
__global__ __launch_bounds__(64) void evo_finish(
    const float* __restrict__ node,     // [1024][64]
    const float* __restrict__ partial,  // [2048][32]
    const float* __restrict__ Wnode,    // [96][64]
    const float* __restrict__ bnode,    // [64]
    const float* __restrict__ lnsc,     // [64]
    const float* __restrict__ lnof,     // [64]
    float* __restrict__ out_node)       // [1024][64]
{
    __shared__ float node_f[64];
    __shared__ float p2n[32];
    const int i   = blockIdx.x;
    const int tid = threadIdx.x;

    node_f[tid] = node[i * 64 + tid];
    if (tid < 32) {
        p2n[tid] = (partial[(2 * i) * 32 + tid] + partial[(2 * i + 1) * 32 + tid])
                   * (1.0f / 1024.0f);
    }
    __syncthreads();

    float acc = node_f[tid] + bnode[tid];
    #pragma unroll 8
    for (int k = 0; k < 64; ++k)
        acc += node_f[k] * Wnode[k * 64 + tid];
    #pragma unroll 8
    for (int k = 0; k < 32; ++k)
        acc += p2n[k] * Wnode[(64 + k) * 64 + tid];

    float s = acc, s2 = acc * acc;
    for (int m = 1; m < 64; m <<= 1) {
        s  += __shfl_xor(s, m);
        s2 += __shfl_xor(s2, m);
    }
    const float mean = s * (1.0f / 64.0f);
    const float var  = s2 * (1.0f / 64.0f) - mean * mean;
    const float y = (acc - mean) * rsqrtf(var + 1e-5f) * lnsc[tid] + lnof[tid];
    out_node[i * 64 + tid] = y;
}

extern "C" void kernel_launch(void* const* d_in, const int* in_sizes, int n_in,
                              void* d_out, int out_size, void* d_ws, size_t ws_size,
                              hipStream_t stream) {
    const float* node  = (const float*)d_in[0];
    const float* pair  = (const float*)d_in[1];
    const float* Wpair = (const float*)d_in[2];
    const float* bpair = (const float*)d_in[3];
    const float* Wnode = (const float*)d_in[4];
    const float* bnode = (const float*)d_in[5];
    const float* lnsc  = (const float*)d_in[6];
    const float* lnof  = (const float*)d_in[7];

    float* niB = (float*)d_ws;                        // [1024][32] f32
    float* njB = niB + LSEQ * EDIM;                   // [1024][32] f32
    unsigned short* wpT = (unsigned short*)(njB + LSEQ * EDIM);  // [32][32] bf16 (2 KB)
    float* partial = (float*)(wpT + EDIM * EDIM);     // [2048][32] f32 (256 KB)

    float* out_node = (float*)d_out;
    float* out_pair = out_node + LSEQ * NDIM;

    evo_pre<<<132, 256, 0, stream>>>(node, Wpair, bpair, niB, njB, wpT);
    evo_main<<<2 * LSEQ, 256, 0, stream>>>(pair, niB, njB, wpT, partial, out_pair);
    evo_finish<<<LSEQ, 64, 0, stream>>>(node, partial, Wnode, bnode, lnsc, lnof,
                                        out_node);
}